// Round 1
// baseline (727.221 us; speedup 1.0000x reference)
//
#include <hip/hip_runtime.h>
#include <cstdint>
#include <cstddef>

// ArcFace: e=l2norm(emb) [1024,512]; w=l2norm(weight) [100000,512];
// cos = clip(e@w^T, -1, 1); at (r, labels[r]): cos(theta+0.5); out = 30*logits.
// Margin closed form: cos(theta+M) = cosM*c - sinM*sqrt(1-c^2)  (theta in [0,pi]).

constexpr int N_ROWS = 1024;
constexpr int DIM    = 512;
constexpr int C_CLS  = 100000;
constexpr int C_PAD  = 100096;   // 782 * 128

#define COS_M 0.87758256189037271612f
#define SIN_M 0.47942553860420300027f

typedef __attribute__((ext_vector_type(8))) __bf16 bf16x8;
typedef __attribute__((ext_vector_type(4))) float  floatx4;

__device__ inline unsigned short f2bf(float f) {
    unsigned int u = __float_as_uint(f);
    u += 0x7FFFu + ((u >> 16) & 1u);   // round-to-nearest-even
    return (unsigned short)(u >> 16);
}

__device__ inline float wave_reduce_sum(float v) {
    v += __shfl_xor(v, 32, 64);
    v += __shfl_xor(v, 16, 64);
    v += __shfl_xor(v, 8, 64);
    v += __shfl_xor(v, 4, 64);
    v += __shfl_xor(v, 2, 64);
    v += __shfl_xor(v, 1, 64);
    return v;
}

__device__ inline void async16(const void* g, void* l) {
    __builtin_amdgcn_global_load_lds(
        (const __attribute__((address_space(1))) void*)g,
        (__attribute__((address_space(3))) void*)l,
        16, 0, 0);
}

// One wave per row: l2-normalize float row -> bf16 row. Rows >= rows_valid -> zeros.
__global__ __launch_bounds__(256) void normalize_rows(
    const float* __restrict__ in, unsigned short* __restrict__ out,
    int rows_valid, int rows_total) {
    int wave = (int)((blockIdx.x * 256u + threadIdx.x) >> 6);
    int lane = threadIdx.x & 63;
    if (wave >= rows_total) return;

    unsigned short* orow = out + (size_t)wave * DIM;
    if (wave < rows_valid) {
        const float4* rp = (const float4*)(in + (size_t)wave * DIM);
        float4 x0 = rp[lane];        // cols 4*lane .. +4
        float4 x1 = rp[64 + lane];   // cols 256 + 4*lane .. +4
        float s = x0.x*x0.x + x0.y*x0.y + x0.z*x0.z + x0.w*x0.w
                + x1.x*x1.x + x1.y*x1.y + x1.z*x1.z + x1.w*x1.w;
        s = wave_reduce_sum(s);
        float inv = 1.0f / fmaxf(sqrtf(s), 1e-12f);
        ushort4 o0, o1;
        o0.x = f2bf(x0.x * inv); o0.y = f2bf(x0.y * inv);
        o0.z = f2bf(x0.z * inv); o0.w = f2bf(x0.w * inv);
        o1.x = f2bf(x1.x * inv); o1.y = f2bf(x1.y * inv);
        o1.z = f2bf(x1.z * inv); o1.w = f2bf(x1.w * inv);
        ((ushort4*)orow)[lane]      = o0;
        ((ushort4*)orow)[64 + lane] = o1;
    } else {
        ushort4 z; z.x = z.y = z.z = z.w = 0;
        ((ushort4*)orow)[lane]      = z;
        ((ushort4*)orow)[64 + lane] = z;
    }
}

// 128x128 tile GEMM (m97 structure): A [1024,512] bf16, W [100096,512] bf16,
// out[r,c] = 30 * clip(dot, -1, 1) with margin at c == labels[r].
__global__ __launch_bounds__(256) void arcface_gemm(
    const unsigned short* __restrict__ A,
    const unsigned short* __restrict__ W,
    const int* __restrict__ labels,
    float* __restrict__ out) {
    __shared__ unsigned short As[128 * 32];  // [m][k], row stride 32 (64 B) — matches lds dest order
    __shared__ unsigned short Bs[128 * 32];  // [n][k]
    __shared__ int labs[128];

    const int tid  = threadIdx.x;
    const int lane = tid & 63;
    const int wv   = tid >> 6;       // 0..3
    const int wr   = wv >> 1;        // wave row quadrant (64 rows)
    const int wc   = wv & 1;         // wave col quadrant (64 cols)
    const int mbase = blockIdx.x * 128;   // M tiles fastest -> W panel shared by adjacent blocks
    const int nbase = blockIdx.y * 128;

    if (tid < 128) labs[tid] = labels[mbase + tid];

    const int srow   = tid >> 2;     // 0..63
    const int schunk = tid & 3;      // 16B chunk within a 64B k-row

    floatx4 acc[4][4];
    for (int i = 0; i < 4; i++)
        for (int j = 0; j < 4; j++)
            acc[i][j] = (floatx4){0.f, 0.f, 0.f, 0.f};

    const unsigned short* Ag = A + (size_t)mbase * DIM;
    const unsigned short* Wg = W + (size_t)nbase * DIM;

    const int kq   = (lane >> 4) * 8;   // k offset of this lane's fragment
    const int mrow = lane & 15;

    for (int k0 = 0; k0 < DIM; k0 += 32) {
        // stage A tile: rows srow, srow+64 ; LDS offset tid*16B == row*64 + chunk*16
        async16(Ag + (size_t)srow * DIM + k0 + schunk * 8,        &As[tid * 8]);
        async16(Ag + (size_t)(srow + 64) * DIM + k0 + schunk * 8, &As[2048 + tid * 8]);
        async16(Wg + (size_t)srow * DIM + k0 + schunk * 8,        &Bs[tid * 8]);
        async16(Wg + (size_t)(srow + 64) * DIM + k0 + schunk * 8, &Bs[2048 + tid * 8]);
        __syncthreads();

        bf16x8 af[4], bfr[4];
        for (int i = 0; i < 4; i++)
            af[i] = *(const bf16x8*)&As[(wr * 64 + i * 16 + mrow) * 32 + kq];
        for (int j = 0; j < 4; j++)
            bfr[j] = *(const bf16x8*)&Bs[(wc * 64 + j * 16 + mrow) * 32 + kq];

        for (int i = 0; i < 4; i++)
            for (int j = 0; j < 4; j++)
                acc[i][j] = __builtin_amdgcn_mfma_f32_16x16x32_bf16(
                    af[i], bfr[j], acc[i][j], 0, 0, 0);
        __syncthreads();
    }

    // Epilogue: C/D layout col = lane&15, row = (lane>>4)*4 + reg
    const int col0 = nbase + wc * 64 + (lane & 15);
    for (int i = 0; i < 4; i++) {
        const int rbase = wr * 64 + i * 16 + (lane >> 4) * 4;
        for (int r = 0; r < 4; r++) {
            const int row  = rbase + r;
            const int grow = mbase + row;
            const int lab  = labs[row];
            float* orow = out + (size_t)grow * C_CLS;
            for (int j = 0; j < 4; j++) {
                const int gc = col0 + j * 16;
                if (gc < C_CLS) {
                    float c = acc[i][j][r];
                    c = fminf(1.0f, fmaxf(-1.0f, c));
                    float v = c;
                    if (gc == lab) {
                        v = COS_M * c - SIN_M * sqrtf(fmaxf(0.0f, 1.0f - c * c));
                    }
                    orow[gc] = 30.0f * v;
                }
            }
        }
    }
}

extern "C" void kernel_launch(void* const* d_in, const int* in_sizes, int n_in,
                              void* d_out, int out_size, void* d_ws, size_t ws_size,
                              hipStream_t stream) {
    const float* emb    = (const float*)d_in[0];
    const float* wgt    = (const float*)d_in[1];
    const int*   labels = (const int*)d_in[2];
    float*       out    = (float*)d_out;

    unsigned short* An = (unsigned short*)d_ws;                       // 1024*512 bf16 = 1 MiB
    unsigned short* Wn = (unsigned short*)((char*)d_ws + (size_t)N_ROWS * DIM * 2);  // 100096*512 bf16

    normalize_rows<<<N_ROWS / 4, 256, 0, stream>>>(emb, An, N_ROWS, N_ROWS);
    normalize_rows<<<C_PAD / 4, 256, 0, stream>>>(wgt, Wn, C_CLS, C_PAD);

    dim3 grid(N_ROWS / 128, C_PAD / 128);   // (8, 782); M fastest for W-panel L2 reuse
    arcface_gemm<<<grid, 256, 0, stream>>>(An, Wn, labels, out);
}